// Round 1
// 736.082 us; speedup vs baseline: 1.0779x; 1.0779x over previous
//
#include <hip/hip_runtime.h>
#include <math.h>

// Problem constants (match reference)
constexpr int H  = 128;   // hidden
constexpr int B  = 512;   // graphs
// Workspace layout per rank (floats):
//   [0,65536)        sum   [B][H]
//   [65536,131072)   gsum  [B][H]
//   [131072,196608)  max   [B][H]
//   [196608,197120)  cnt   [B]
constexpr int RANK_STRIDE = 3 * B * H + B;  // 197120 floats
constexpr int TOTAL_WS    = 3 * RANK_STRIDE;

constexpr int ROWS_PER_WAVE  = 128;
constexpr int ROWS_PER_BLOCK = 4 * ROWS_PER_WAVE;  // 4 waves/block = 512 rows

__device__ __forceinline__ float atomicMaxF(float* addr, float val) {
  // bit trick: int-max for >=0, uint-min for <0; buffer init to -inf
  if (val >= 0.f) {
    return __int_as_float(atomicMax((int*)addr, __float_as_int(val)));
  } else {
    return __uint_as_float(atomicMin((unsigned int*)addr, __float_as_uint(val)));
  }
}

__global__ __launch_bounds__(256) void init_ws_kernel(float* ws) {
  int i = blockIdx.x * blockDim.x + threadIdx.x;
  if (i >= TOTAL_WS) return;
  int o = i % RANK_STRIDE;
  bool ismax = (o >= 2 * B * H) && (o < 3 * B * H);
  ws[i] = ismax ? __int_as_float(0xFF800000) : 0.0f;  // -inf for max, 0 else
}

// x + dpp_move(x, ctrl) — pure VALU-pipe cross-lane add (no LDS round-trip).
// ctrl: 0xB1 = quad_perm[1,0,3,2] (xor1), 0x4E = quad_perm[2,3,0,1] (xor2),
//       0x124 = row_ror:4, 0x128 = row_ror:8 (together sum quads within row16).
template <int CTRL>
__device__ __forceinline__ float dpp_add(float x) {
  int mi = __builtin_amdgcn_update_dpp(0, __float_as_int(x), CTRL, 0xF, 0xF, true);
  return x + __int_as_float(mi);
}

// Fused streaming kernel over all 3 ranks.
// Layout: lane l handles cols 4*(l&31)..+3; lanes 0..31 = even row of a pair,
// lanes 32..63 = odd row. One float4 load instruction fetches 2 full rows.
// Gate dot product: 4 DPP VALU adds + one ds_swizzle (xor16) per row — the
// old 5-deep ds_swizzle chain was the dominant lgkmcnt latency chain.
// Fast path is software-pipelined: batch g+1's 8 float4 loads are issued
// before batch g's compute, with cross-chunk prefetch of the next batch 0.
__global__ __launch_bounds__(256) void rank_fused_kernel(
    const float* __restrict__ h0, const int* __restrict__ b0,
    const float* __restrict__ Wg0, const float* __restrict__ bg0, int N0, int nb0,
    const float* __restrict__ h1, const int* __restrict__ b1,
    const float* __restrict__ Wg1, const float* __restrict__ bg1, int N1, int nb1,
    const float* __restrict__ h2, const int* __restrict__ b2,
    const float* __restrict__ Wg2, const float* __restrict__ bg2, int N2,
    float* __restrict__ ws)
{
  const int blk = blockIdx.x;
  const float* h; const int* b; const float* Wg; const float* bg;
  float* base; int N; int lblk;
  if (blk < nb0) {
    h = h0; b = b0; Wg = Wg0; bg = bg0; base = ws;                   N = N0; lblk = blk;
  } else if (blk < nb0 + nb1) {
    h = h1; b = b1; Wg = Wg1; bg = bg1; base = ws + RANK_STRIDE;     N = N1; lblk = blk - nb0;
  } else {
    h = h2; b = b2; Wg = Wg2; bg = bg2; base = ws + 2 * RANK_STRIDE; N = N2; lblk = blk - nb0 - nb1;
  }

  const int lane = threadIdx.x & 63;
  const int wv   = threadIdx.x >> 6;
  const int half = lane >> 5;      // 0: even row of pair, 1: odd row
  const int c    = lane & 31;      // column group (4 floats)

  const int wstart = (lblk * 4 + wv) * ROWS_PER_WAVE;
  if (wstart >= N) return;
  const int wend = min(wstart + ROWS_PER_WAVE, N);

  float* __restrict__ sumb  = base;
  float* __restrict__ gsumb = base + B * H;
  float* __restrict__ maxb  = base + 2 * B * H;
  float* __restrict__ cntb  = base + 3 * B * H;

  const float4 wg  = ((const float4*)Wg)[c];
  const float  bgv = bg[0];

  // preload the wave's segment ids into 2 registers (coalesced, then shuffle)
  const int bv0 = b[min(wstart + lane, N - 1)];
  const int bv1 = b[min(wstart + 64 + lane, N - 1)];

  float4 s  = {0.f, 0.f, 0.f, 0.f};
  float4 gq = {0.f, 0.f, 0.f, 0.f};
  float4 m  = {-INFINITY, -INFINITY, -INFINITY, -INFINITY};
  int cnt = 0;
  int cur = -1;

  auto flushLane = [&]() {
    if (cur >= 0) {
      const int bi = cur * H + c * 4;
      atomicAdd(sumb + bi + 0, s.x);  atomicAdd(sumb + bi + 1, s.y);
      atomicAdd(sumb + bi + 2, s.z);  atomicAdd(sumb + bi + 3, s.w);
      atomicAdd(gsumb + bi + 0, gq.x); atomicAdd(gsumb + bi + 1, gq.y);
      atomicAdd(gsumb + bi + 2, gq.z); atomicAdd(gsumb + bi + 3, gq.w);
      atomicMaxF(maxb + bi + 0, m.x); atomicMaxF(maxb + bi + 1, m.y);
      atomicMaxF(maxb + bi + 2, m.z); atomicMaxF(maxb + bi + 3, m.w);
      if (c == 0 && cnt) atomicAdd(cntb + cur, (float)cnt);
      s = {0.f, 0.f, 0.f, 0.f};
      gq = {0.f, 0.f, 0.f, 0.f};
      m = {-INFINITY, -INFINITY, -INFINITY, -INFINITY};
      cnt = 0;
    }
  };

  // Full-row dot within each 32-lane half, then sigmoid.
  // xor1/xor2 via quad_perm DPP, xor4+xor8 via row_ror DPP (all VALU pipe),
  // xor16 via a single ds_swizzle (the only LDS-pipe op).
  auto gateOf = [&](float4 v) -> float {
    float p = fmaf(v.x, wg.x, fmaf(v.y, wg.y, fmaf(v.z, wg.z, v.w * wg.w)));
    p = dpp_add<0xB1>(p);    // + lane^1
    p = dpp_add<0x4E>(p);    // + lane^2   -> quad sums
    p = dpp_add<0x124>(p);   // + row_ror:4
    p = dpp_add<0x128>(p);   // + row_ror:8 -> full 16-lane row sum in all lanes
    p += __int_as_float(__builtin_amdgcn_ds_swizzle(__float_as_int(p), 0x401F)); // ^16
    return 1.0f / (1.0f + __expf(-(p + bgv)));
  };

  auto accum = [&](float4 v, float gt) {
    s.x += v.x; s.y += v.y; s.z += v.z; s.w += v.w;
    gq.x = fmaf(gt, v.x, gq.x); gq.y = fmaf(gt, v.y, gq.y);
    gq.z = fmaf(gt, v.z, gq.z); gq.w = fmaf(gt, v.w, gq.w);
    m.x = fmaxf(m.x, v.x); m.y = fmaxf(m.y, v.y);
    m.z = fmaxf(m.z, v.z); m.w = fmaxf(m.w, v.w);
  };

  const float4* __restrict__ hp = (const float4*)h;

  // load one 8-pair batch (16 rows starting at `baseRow`)
  auto LOADB = [&](float4* dst, int baseRow) {
    const float4* rp = hp + (size_t)baseRow * 32 + c;
    #pragma unroll
    for (int i = 0; i < 8; ++i) dst[i] = rp[(size_t)(2 * i + half) * 32];
  };

  float4 cbuf[8];
  bool pre = false;   // cbuf holds batch0 of the chunk at current r

  int r = wstart;
  while (r + 64 <= wend) {
    const int bv = (r - wstart < 64) ? bv0 : bv1;
    const int sA = __shfl(bv, 0);
    const int sB = __shfl(bv, 63);
    if (sA == sB) {
      // fast path: whole 64-row chunk in one segment, branch-free,
      // double-buffered loads (next batch in flight during compute)
      if (sA != cur) { flushLane(); cur = sA; }
      if (!pre) LOADB(cbuf, r);
      const bool pnext = (r + 128 <= wend);
      float4 nbuf[8];
      #pragma unroll
      for (int g = 0; g < 4; ++g) {
        if (g < 3) {
          LOADB(nbuf, r + (g + 1) * 16);
        } else if (pnext) {
          LOADB(nbuf, r + 64);            // cross-chunk prefetch (batch 0)
        }
        #pragma unroll
        for (int i = 0; i < 8; ++i) {
          const float gt = gateOf(cbuf[i]);
          accum(cbuf[i], gt);
        }
        #pragma unroll
        for (int i = 0; i < 8; ++i) cbuf[i] = nbuf[i];
      }
      pre = pnext;
      cnt += 32;  // 32 rows per half
    } else {
      // slow path: per-pair, per-lane segment tracking
      #pragma unroll 4
      for (int i = 0; i < 32; ++i) {
        const int seg = __shfl(bv, 2 * i + half);
        const float4 v = hp[(size_t)(r + 2 * i + half) * 32 + c];
        const float gt = gateOf(v);
        if (seg != cur) { flushLane(); cur = seg; }
        accum(v, gt);
        ++cnt;
      }
      pre = false;
    }
    r += 64;
  }
  // tail pairs
  while (r + 2 <= wend) {
    const int o = r - wstart;
    const int bv = (o < 64) ? bv0 : bv1;
    const int seg = __shfl(bv, (o & 63) + half);
    const float4 v = hp[(size_t)(r + half) * 32 + c];
    const float gt = gateOf(v);
    if (seg != cur) { flushLane(); cur = seg; }
    accum(v, gt);
    ++cnt;
    r += 2;
  }
  // final single row (lower half only; both halves loaded the same row)
  if (r < wend) {
    const int o = r - wstart;
    const int bv = (o < 64) ? bv0 : bv1;
    const int seg = __shfl(bv, o & 63);
    const float4 v = hp[(size_t)r * 32 + c];
    const float gt = gateOf(v);
    if (half == 0) {
      if (seg != cur) { flushLane(); cur = seg; }
      accum(v, gt);
      ++cnt;
    }
  }

  // merge half pairs before the final flush: the two halves almost always
  // ended in the same segment -> half0 flushes the pair-sum, half1 skips.
  // Halves the end-of-wave atomic traffic (the dominant WRITE_SIZE source).
  {
    const int   ocur = __shfl_xor(cur, 32);
    const float osx = __shfl_xor(s.x, 32), osy = __shfl_xor(s.y, 32);
    const float osz = __shfl_xor(s.z, 32), osw = __shfl_xor(s.w, 32);
    const float ogx = __shfl_xor(gq.x, 32), ogy = __shfl_xor(gq.y, 32);
    const float ogz = __shfl_xor(gq.z, 32), ogw = __shfl_xor(gq.w, 32);
    const float omx = __shfl_xor(m.x, 32), omy = __shfl_xor(m.y, 32);
    const float omz = __shfl_xor(m.z, 32), omw = __shfl_xor(m.w, 32);
    const int   ocnt = __shfl_xor(cnt, 32);
    if (ocur == cur && cur >= 0) {
      if (half == 0) {
        s.x += osx; s.y += osy; s.z += osz; s.w += osw;
        gq.x += ogx; gq.y += ogy; gq.z += ogz; gq.w += ogw;
        m.x = fmaxf(m.x, omx); m.y = fmaxf(m.y, omy);
        m.z = fmaxf(m.z, omz); m.w = fmaxf(m.w, omw);
        cnt += ocnt;
      } else {
        cur = -1;  // partner flushes for both halves
      }
    }
  }
  flushLane();
}

__device__ __forceinline__ float siluf(float x) {
  return x / (1.0f + __expf(-x));
}

// 128 threads, 4 graphs per block (grid = B/4 = 128).
__global__ __launch_bounds__(128) void finalize_kernel(
    const float* __restrict__ ws,
    const float* __restrict__ Wp0, const float* __restrict__ bp0,
    const float* __restrict__ Wp1, const float* __restrict__ bp1,
    const float* __restrict__ Wp2, const float* __restrict__ bp2,
    const float* __restrict__ gamma, const float* __restrict__ beta,
    const float* __restrict__ W1, const float* __restrict__ b1f,
    const float* __restrict__ W2, const float* __restrict__ b2f,
    float* __restrict__ out)
{
  __shared__ float aggL[4][4 * H];   // 8 KB
  __shared__ float state[4][3 * H];  // 6 KB
  __shared__ float red[8];

  const int j = threadIdx.x;         // 0..127
  const int lane = j & 63;
  const int wv = j >> 6;             // 0..1
  const int gbase = blockIdx.x * 4;

  const float* Wp[3] = {Wp0, Wp1, Wp2};
  const float* bp[3] = {bp0, bp1, bp2};

  for (int k = 0; k < 3; ++k) {
    const float* sumb  = ws + k * RANK_STRIDE;
    const float* gsumb = sumb + B * H;
    const float* maxb  = sumb + 2 * B * H;
    const float* cntb  = sumb + 3 * B * H;

    for (int g = 0; g < 4; ++g) {
      const int bidx = gbase + g;
      const float cc = cntb[bidx];
      const float cm = fmaxf(cc, 1.0f);
      const float sv = sumb[bidx * H + j];
      const float mv = maxb[bidx * H + j];
      const float gv = gsumb[bidx * H + j];
      aggL[g][j]         = sv;
      aggL[g][H + j]     = sv / cm;
      aggL[g][2 * H + j] = (cc > 0.f) ? mv : 0.f;
      aggL[g][3 * H + j] = gv;
    }
    __syncthreads();

    const float bpv = bp[k][j];
    float r0 = bpv, r1 = bpv, r2 = bpv, r3 = bpv;
    const float* W = Wp[k];
    for (int i = 0; i < 4 * H; ++i) {
      const float w = W[i * H + j];        // coalesced; L2-resident
      r0 = fmaf(aggL[0][i], w, r0);        // LDS broadcast reads
      r1 = fmaf(aggL[1][i], w, r1);
      r2 = fmaf(aggL[2][i], w, r2);
      r3 = fmaf(aggL[3][i], w, r3);
    }
    state[0][k * H + j] = r0;
    state[1][k * H + j] = r1;
    state[2][k * H + j] = r2;
    state[3][k * H + j] = r3;
    __syncthreads();
  }

  // LayerNorm + SiLU per graph (384 elems, 3 per thread)
  for (int g = 0; g < 4; ++g) {
    const float v0 = state[g][j];
    const float v1 = state[g][H + j];
    const float v2 = state[g][2 * H + j];
    float ps = v0 + v1 + v2;
    float pq = v0 * v0 + v1 * v1 + v2 * v2;
    for (int mm = 1; mm < 64; mm <<= 1) {
      ps += __shfl_xor(ps, mm);
      pq += __shfl_xor(pq, mm);
    }
    if (lane == 0) { red[wv * 2] = ps; red[wv * 2 + 1] = pq; }
    __syncthreads();
    const float ts = red[0] + red[2];
    const float tq = red[1] + red[3];
    const float mu  = ts * (1.0f / 384.0f);
    const float var = tq * (1.0f / 384.0f) - mu * mu;
    const float inv = rsqrtf(var + 1e-5f);
    float x0 = (v0 - mu) * inv * gamma[j]         + beta[j];
    float x1 = (v1 - mu) * inv * gamma[H + j]     + beta[H + j];
    float x2 = (v2 - mu) * inv * gamma[2 * H + j] + beta[2 * H + j];
    state[g][j]         = siluf(x0);
    state[g][H + j]     = siluf(x1);
    state[g][2 * H + j] = siluf(x2);
    __syncthreads();
  }

  // FC1: x = silu(state @ W1 + b1f); weight load shared across 4 graphs
  const float b1v = b1f[j];
  float a0 = b1v, a1 = b1v, a2 = b1v, a3 = b1v;
  for (int i = 0; i < 3 * H; ++i) {
    const float w = W1[i * H + j];
    a0 = fmaf(state[0][i], w, a0);
    a1 = fmaf(state[1][i], w, a1);
    a2 = fmaf(state[2][i], w, a2);
    a3 = fmaf(state[3][i], w, a3);
  }
  a0 = siluf(a0); a1 = siluf(a1); a2 = siluf(a2); a3 = siluf(a3);

  // FC2: dot over 128
  const float w2 = W2[j];
  float p0 = a0 * w2, p1 = a1 * w2, p2 = a2 * w2, p3 = a3 * w2;
  for (int mm = 1; mm < 64; mm <<= 1) {
    p0 += __shfl_xor(p0, mm);
    p1 += __shfl_xor(p1, mm);
    p2 += __shfl_xor(p2, mm);
    p3 += __shfl_xor(p3, mm);
  }
  __syncthreads();  // red[] reuse
  if (lane == 0) {
    red[wv * 4 + 0] = p0; red[wv * 4 + 1] = p1;
    red[wv * 4 + 2] = p2; red[wv * 4 + 3] = p3;
  }
  __syncthreads();
  if (j < 4) out[gbase + j] = red[j] + red[4 + j] + b2f[0];
}

extern "C" void kernel_launch(void* const* d_in, const int* in_sizes, int n_in,
                              void* d_out, int out_size, void* d_ws, size_t ws_size,
                              hipStream_t stream) {
  const float* h0  = (const float*)d_in[0];
  const float* h1  = (const float*)d_in[1];
  const float* h2  = (const float*)d_in[2];
  const int*   b0  = (const int*)d_in[3];
  const int*   b1  = (const int*)d_in[4];
  const int*   b2  = (const int*)d_in[5];
  const float* Wg0 = (const float*)d_in[6];
  const float* bg0 = (const float*)d_in[7];
  const float* Wg1 = (const float*)d_in[8];
  const float* bg1 = (const float*)d_in[9];
  const float* Wg2 = (const float*)d_in[10];
  const float* bg2 = (const float*)d_in[11];
  const float* Wp0 = (const float*)d_in[12];
  const float* bp0 = (const float*)d_in[13];
  const float* Wp1 = (const float*)d_in[14];
  const float* bp1 = (const float*)d_in[15];
  const float* Wp2 = (const float*)d_in[16];
  const float* bp2 = (const float*)d_in[17];
  const float* gamma = (const float*)d_in[18];
  const float* beta  = (const float*)d_in[19];
  const float* W1  = (const float*)d_in[20];
  const float* b1f = (const float*)d_in[21];
  const float* W2  = (const float*)d_in[22];
  const float* b2f = (const float*)d_in[23];

  const int N0 = in_sizes[3];
  const int N1 = in_sizes[4];
  const int N2 = in_sizes[5];

  float* ws = (float*)d_ws;

  // init workspace (sums/cnt = 0, max = -inf)
  {
    int blocks = (TOTAL_WS + 255) / 256;
    hipLaunchKernelGGL(init_ws_kernel, dim3(blocks), dim3(256), 0, stream, ws);
  }

  // fused streaming pass over all 3 ranks
  const int nb0 = (N0 + ROWS_PER_BLOCK - 1) / ROWS_PER_BLOCK;
  const int nb1 = (N1 + ROWS_PER_BLOCK - 1) / ROWS_PER_BLOCK;
  const int nb2 = (N2 + ROWS_PER_BLOCK - 1) / ROWS_PER_BLOCK;
  hipLaunchKernelGGL(rank_fused_kernel, dim3(nb0 + nb1 + nb2), dim3(256), 0, stream,
                     h0, b0, Wg0, bg0, N0, nb0,
                     h1, b1, Wg1, bg1, N1, nb1,
                     h2, b2, Wg2, bg2, N2,
                     ws);

  // fused head: agg@Wp -> LN -> SiLU -> FC1 -> SiLU -> FC2
  hipLaunchKernelGGL(finalize_kernel, dim3(B / 4), dim3(128), 0, stream,
                     ws, Wp0, bp0, Wp1, bp1, Wp2, bp2,
                     gamma, beta, W1, b1f, W2, b2f, (float*)d_out);
}

// Round 2
// 734.958 us; speedup vs baseline: 1.0795x; 1.0015x over previous
//
#include <hip/hip_runtime.h>
#include <math.h>

// Problem constants (match reference)
constexpr int H  = 128;   // hidden
constexpr int B  = 512;   // graphs
// Workspace layout per rank (floats):
//   [0,65536)        sum   [B][H]
//   [65536,131072)   gsum  [B][H]
//   [131072,196608)  max   [B][H]
//   [196608,197120)  cnt   [B]
constexpr int RANK_STRIDE = 3 * B * H + B;  // 197120 floats
constexpr int TOTAL_WS    = 3 * RANK_STRIDE;

constexpr int ROWS_PER_WAVE  = 128;
constexpr int ROWS_PER_BLOCK = 4 * ROWS_PER_WAVE;  // 4 waves/block = 512 rows

__device__ __forceinline__ float atomicMaxF(float* addr, float val) {
  // bit trick: int-max for >=0, uint-min for <0; buffer init to -inf
  if (val >= 0.f) {
    return __int_as_float(atomicMax((int*)addr, __float_as_int(val)));
  } else {
    return __uint_as_float(atomicMin((unsigned int*)addr, __float_as_uint(val)));
  }
}

__global__ __launch_bounds__(256) void init_ws_kernel(float* ws) {
  int i = blockIdx.x * blockDim.x + threadIdx.x;
  if (i >= TOTAL_WS) return;
  int o = i % RANK_STRIDE;
  bool ismax = (o >= 2 * B * H) && (o < 3 * B * H);
  ws[i] = ismax ? __int_as_float(0xFF800000) : 0.0f;  // -inf for max, 0 else
}

// x + dpp_move(x, ctrl) — pure VALU-pipe cross-lane add (no LDS round-trip).
// ctrl: 0xB1 = quad_perm[1,0,3,2] (xor1), 0x4E = quad_perm[2,3,0,1] (xor2),
//       0x124 = row_ror:4, 0x128 = row_ror:8 (together sum quads within row16).
template <int CTRL>
__device__ __forceinline__ float dpp_add(float x) {
  int mi = __builtin_amdgcn_update_dpp(0, __float_as_int(x), CTRL, 0xF, 0xF, true);
  return x + __int_as_float(mi);
}

// Fused streaming kernel over all 3 ranks.
// Layout: lane l handles cols 4*(l&31)..+3; lanes 0..31 = even row of a pair,
// lanes 32..63 = odd row. One float4 load instruction fetches 2 full rows.
// Gate dot product: 4 DPP VALU adds + one ds_swizzle (xor16) per row.
// Fast path: compile-time ping-pong (named regs A0..A3 / B0..B3, NO array
// rotation copies) so the compiler emits counted vmcnt waits and batch k+1's
// 4 float4 loads stay in flight through batch k's compute. 8-row batches
// keep the buffer live-set at 32 VGPRs (spill-free; round-1's 64-reg
// buffers + rotation copy forced vmcnt(0) drains + scratch traffic).
__global__ __launch_bounds__(256) void rank_fused_kernel(
    const float* __restrict__ h0, const int* __restrict__ b0,
    const float* __restrict__ Wg0, const float* __restrict__ bg0, int N0, int nb0,
    const float* __restrict__ h1, const int* __restrict__ b1,
    const float* __restrict__ Wg1, const float* __restrict__ bg1, int N1, int nb1,
    const float* __restrict__ h2, const int* __restrict__ b2,
    const float* __restrict__ Wg2, const float* __restrict__ bg2, int N2,
    float* __restrict__ ws)
{
  const int blk = blockIdx.x;
  const float* h; const int* b; const float* Wg; const float* bg;
  float* base; int N; int lblk;
  if (blk < nb0) {
    h = h0; b = b0; Wg = Wg0; bg = bg0; base = ws;                   N = N0; lblk = blk;
  } else if (blk < nb0 + nb1) {
    h = h1; b = b1; Wg = Wg1; bg = bg1; base = ws + RANK_STRIDE;     N = N1; lblk = blk - nb0;
  } else {
    h = h2; b = b2; Wg = Wg2; bg = bg2; base = ws + 2 * RANK_STRIDE; N = N2; lblk = blk - nb0 - nb1;
  }

  const int lane = threadIdx.x & 63;
  const int wv   = threadIdx.x >> 6;
  const int half = lane >> 5;      // 0: even row of pair, 1: odd row
  const int c    = lane & 31;      // column group (4 floats)

  const int wstart = (lblk * 4 + wv) * ROWS_PER_WAVE;
  if (wstart >= N) return;
  const int wend = min(wstart + ROWS_PER_WAVE, N);

  float* __restrict__ sumb  = base;
  float* __restrict__ gsumb = base + B * H;
  float* __restrict__ maxb  = base + 2 * B * H;
  float* __restrict__ cntb  = base + 3 * B * H;

  const float4 wg  = ((const float4*)Wg)[c];
  const float  bgv = bg[0];

  // preload the wave's segment ids into 2 registers (coalesced, then shuffle)
  const int bv0 = b[min(wstart + lane, N - 1)];
  const int bv1 = b[min(wstart + 64 + lane, N - 1)];

  float4 s  = {0.f, 0.f, 0.f, 0.f};
  float4 gq = {0.f, 0.f, 0.f, 0.f};
  float4 m  = {-INFINITY, -INFINITY, -INFINITY, -INFINITY};
  int cnt = 0;
  int cur = -1;

  auto flushLane = [&]() {
    if (cur >= 0) {
      const int bi = cur * H + c * 4;
      atomicAdd(sumb + bi + 0, s.x);  atomicAdd(sumb + bi + 1, s.y);
      atomicAdd(sumb + bi + 2, s.z);  atomicAdd(sumb + bi + 3, s.w);
      atomicAdd(gsumb + bi + 0, gq.x); atomicAdd(gsumb + bi + 1, gq.y);
      atomicAdd(gsumb + bi + 2, gq.z); atomicAdd(gsumb + bi + 3, gq.w);
      atomicMaxF(maxb + bi + 0, m.x); atomicMaxF(maxb + bi + 1, m.y);
      atomicMaxF(maxb + bi + 2, m.z); atomicMaxF(maxb + bi + 3, m.w);
      if (c == 0 && cnt) atomicAdd(cntb + cur, (float)cnt);
      s = {0.f, 0.f, 0.f, 0.f};
      gq = {0.f, 0.f, 0.f, 0.f};
      m = {-INFINITY, -INFINITY, -INFINITY, -INFINITY};
      cnt = 0;
    }
  };

  // Full-row dot within each 32-lane half, then sigmoid.
  // xor1/xor2 via quad_perm DPP, xor4+xor8 via row_ror DPP (all VALU pipe),
  // xor16 via a single ds_swizzle (the only LDS-pipe op).
  auto gateOf = [&](float4 v) -> float {
    float p = fmaf(v.x, wg.x, fmaf(v.y, wg.y, fmaf(v.z, wg.z, v.w * wg.w)));
    p = dpp_add<0xB1>(p);    // + lane^1
    p = dpp_add<0x4E>(p);    // + lane^2   -> quad sums
    p = dpp_add<0x124>(p);   // + row_ror:4
    p = dpp_add<0x128>(p);   // + row_ror:8 -> full 16-lane row sum in all lanes
    p += __int_as_float(__builtin_amdgcn_ds_swizzle(__float_as_int(p), 0x401F)); // ^16
    return 1.0f / (1.0f + __expf(-(p + bgv)));
  };

  auto accum = [&](float4 v, float gt) {
    s.x += v.x; s.y += v.y; s.z += v.z; s.w += v.w;
    gq.x = fmaf(gt, v.x, gq.x); gq.y = fmaf(gt, v.y, gq.y);
    gq.z = fmaf(gt, v.z, gq.z); gq.w = fmaf(gt, v.w, gq.w);
    m.x = fmaxf(m.x, v.x); m.y = fmaxf(m.y, v.y);
    m.z = fmaxf(m.z, v.z); m.w = fmaxf(m.w, v.w);
  };

  const float4* __restrict__ hp = (const float4*)h;

  // issue the 4 float4 loads of one 8-row batch (rows baseRow .. baseRow+7)
  auto LOADQ = [&](float4& d0, float4& d1, float4& d2, float4& d3, int baseRow) {
    const float4* rp = hp + (size_t)baseRow * 32 + c;
    d0 = rp[(size_t)(0 + half) * 32];
    d1 = rp[(size_t)(2 + half) * 32];
    d2 = rp[(size_t)(4 + half) * 32];
    d3 = rp[(size_t)(6 + half) * 32];
  };
  auto COMPQ = [&](const float4& v0, const float4& v1,
                   const float4& v2, const float4& v3) {
    { const float gt = gateOf(v0); accum(v0, gt); }
    { const float gt = gateOf(v1); accum(v1, gt); }
    { const float gt = gateOf(v2); accum(v2, gt); }
    { const float gt = gateOf(v3); accum(v3, gt); }
  };

  float4 A0, A1, A2, A3;   // ping
  float4 B0, B1, B2, B3;   // pong
  bool preA = false;       // A holds rows r..r+7 (batch 0 of current chunk)

  int r = wstart;
  while (r + 64 <= wend) {
    const int bv = (r - wstart < 64) ? bv0 : bv1;
    const int sA = __shfl(bv, 0);
    const int sB = __shfl(bv, 63);
    if (sA == sB) {
      // fast path: whole 64-row chunk in one segment; 8 batches of 8 rows,
      // ping-pong pipelined: batch k+1 issues before batch k computes.
      if (sA != cur) { flushLane(); cur = sA; }
      if (!preA) LOADQ(A0, A1, A2, A3, r);
      LOADQ(B0, B1, B2, B3, r +  8);  COMPQ(A0, A1, A2, A3);
      LOADQ(A0, A1, A2, A3, r + 16);  COMPQ(B0, B1, B2, B3);
      LOADQ(B0, B1, B2, B3, r + 24);  COMPQ(A0, A1, A2, A3);
      LOADQ(A0, A1, A2, A3, r + 32);  COMPQ(B0, B1, B2, B3);
      LOADQ(B0, B1, B2, B3, r + 40);  COMPQ(A0, A1, A2, A3);
      LOADQ(A0, A1, A2, A3, r + 48);  COMPQ(B0, B1, B2, B3);
      LOADQ(B0, B1, B2, B3, r + 56);  COMPQ(A0, A1, A2, A3);
      const bool pnext = (r + 128 <= wend);
      if (pnext) LOADQ(A0, A1, A2, A3, r + 64);  // cross-chunk prefetch
      COMPQ(B0, B1, B2, B3);
      preA = pnext;
      cnt += 32;  // 32 rows per half
    } else {
      // slow path: per-pair, per-lane segment tracking
      #pragma unroll 4
      for (int i = 0; i < 32; ++i) {
        const int seg = __shfl(bv, 2 * i + half);
        const float4 v = hp[(size_t)(r + 2 * i + half) * 32 + c];
        const float gt = gateOf(v);
        if (seg != cur) { flushLane(); cur = seg; }
        accum(v, gt);
        ++cnt;
      }
      preA = false;
    }
    r += 64;
  }
  // tail pairs
  while (r + 2 <= wend) {
    const int o = r - wstart;
    const int bv = (o < 64) ? bv0 : bv1;
    const int seg = __shfl(bv, (o & 63) + half);
    const float4 v = hp[(size_t)(r + half) * 32 + c];
    const float gt = gateOf(v);
    if (seg != cur) { flushLane(); cur = seg; }
    accum(v, gt);
    ++cnt;
    r += 2;
  }
  // final single row (lower half only; both halves loaded the same row)
  if (r < wend) {
    const int o = r - wstart;
    const int bv = (o < 64) ? bv0 : bv1;
    const int seg = __shfl(bv, o & 63);
    const float4 v = hp[(size_t)r * 32 + c];
    const float gt = gateOf(v);
    if (half == 0) {
      if (seg != cur) { flushLane(); cur = seg; }
      accum(v, gt);
      ++cnt;
    }
  }

  // merge half pairs before the final flush: the two halves almost always
  // ended in the same segment -> half0 flushes the pair-sum, half1 skips.
  {
    const int   ocur = __shfl_xor(cur, 32);
    const float osx = __shfl_xor(s.x, 32), osy = __shfl_xor(s.y, 32);
    const float osz = __shfl_xor(s.z, 32), osw = __shfl_xor(s.w, 32);
    const float ogx = __shfl_xor(gq.x, 32), ogy = __shfl_xor(gq.y, 32);
    const float ogz = __shfl_xor(gq.z, 32), ogw = __shfl_xor(gq.w, 32);
    const float omx = __shfl_xor(m.x, 32), omy = __shfl_xor(m.y, 32);
    const float omz = __shfl_xor(m.z, 32), omw = __shfl_xor(m.w, 32);
    const int   ocnt = __shfl_xor(cnt, 32);
    if (ocur == cur && cur >= 0) {
      if (half == 0) {
        s.x += osx; s.y += osy; s.z += osz; s.w += osw;
        gq.x += ogx; gq.y += ogy; gq.z += ogz; gq.w += ogw;
        m.x = fmaxf(m.x, omx); m.y = fmaxf(m.y, omy);
        m.z = fmaxf(m.z, omz); m.w = fmaxf(m.w, omw);
        cnt += ocnt;
      } else {
        cur = -1;  // partner flushes for both halves
      }
    }
  }
  flushLane();
}

__device__ __forceinline__ float siluf(float x) {
  return x / (1.0f + __expf(-x));
}

// 128 threads, 4 graphs per block (grid = B/4 = 128).
__global__ __launch_bounds__(128) void finalize_kernel(
    const float* __restrict__ ws,
    const float* __restrict__ Wp0, const float* __restrict__ bp0,
    const float* __restrict__ Wp1, const float* __restrict__ bp1,
    const float* __restrict__ Wp2, const float* __restrict__ bp2,
    const float* __restrict__ gamma, const float* __restrict__ beta,
    const float* __restrict__ W1, const float* __restrict__ b1f,
    const float* __restrict__ W2, const float* __restrict__ b2f,
    float* __restrict__ out)
{
  __shared__ float aggL[4][4 * H];   // 8 KB
  __shared__ float state[4][3 * H];  // 6 KB
  __shared__ float red[8];

  const int j = threadIdx.x;         // 0..127
  const int lane = j & 63;
  const int wv = j >> 6;             // 0..1
  const int gbase = blockIdx.x * 4;

  const float* Wp[3] = {Wp0, Wp1, Wp2};
  const float* bp[3] = {bp0, bp1, bp2};

  for (int k = 0; k < 3; ++k) {
    const float* sumb  = ws + k * RANK_STRIDE;
    const float* gsumb = sumb + B * H;
    const float* maxb  = sumb + 2 * B * H;
    const float* cntb  = sumb + 3 * B * H;

    for (int g = 0; g < 4; ++g) {
      const int bidx = gbase + g;
      const float cc = cntb[bidx];
      const float cm = fmaxf(cc, 1.0f);
      const float sv = sumb[bidx * H + j];
      const float mv = maxb[bidx * H + j];
      const float gv = gsumb[bidx * H + j];
      aggL[g][j]         = sv;
      aggL[g][H + j]     = sv / cm;
      aggL[g][2 * H + j] = (cc > 0.f) ? mv : 0.f;
      aggL[g][3 * H + j] = gv;
    }
    __syncthreads();

    const float bpv = bp[k][j];
    float r0 = bpv, r1 = bpv, r2 = bpv, r3 = bpv;
    const float* W = Wp[k];
    for (int i = 0; i < 4 * H; ++i) {
      const float w = W[i * H + j];        // coalesced; L2-resident
      r0 = fmaf(aggL[0][i], w, r0);        // LDS broadcast reads
      r1 = fmaf(aggL[1][i], w, r1);
      r2 = fmaf(aggL[2][i], w, r2);
      r3 = fmaf(aggL[3][i], w, r3);
    }
    state[0][k * H + j] = r0;
    state[1][k * H + j] = r1;
    state[2][k * H + j] = r2;
    state[3][k * H + j] = r3;
    __syncthreads();
  }

  // LayerNorm + SiLU per graph (384 elems, 3 per thread)
  for (int g = 0; g < 4; ++g) {
    const float v0 = state[g][j];
    const float v1 = state[g][H + j];
    const float v2 = state[g][2 * H + j];
    float ps = v0 + v1 + v2;
    float pq = v0 * v0 + v1 * v1 + v2 * v2;
    for (int mm = 1; mm < 64; mm <<= 1) {
      ps += __shfl_xor(ps, mm);
      pq += __shfl_xor(pq, mm);
    }
    if (lane == 0) { red[wv * 2] = ps; red[wv * 2 + 1] = pq; }
    __syncthreads();
    const float ts = red[0] + red[2];
    const float tq = red[1] + red[3];
    const float mu  = ts * (1.0f / 384.0f);
    const float var = tq * (1.0f / 384.0f) - mu * mu;
    const float inv = rsqrtf(var + 1e-5f);
    float x0 = (v0 - mu) * inv * gamma[j]         + beta[j];
    float x1 = (v1 - mu) * inv * gamma[H + j]     + beta[H + j];
    float x2 = (v2 - mu) * inv * gamma[2 * H + j] + beta[2 * H + j];
    state[g][j]         = siluf(x0);
    state[g][H + j]     = siluf(x1);
    state[g][2 * H + j] = siluf(x2);
    __syncthreads();
  }

  // FC1: x = silu(state @ W1 + b1f); weight load shared across 4 graphs
  const float b1v = b1f[j];
  float a0 = b1v, a1 = b1v, a2 = b1v, a3 = b1v;
  for (int i = 0; i < 3 * H; ++i) {
    const float w = W1[i * H + j];
    a0 = fmaf(state[0][i], w, a0);
    a1 = fmaf(state[1][i], w, a1);
    a2 = fmaf(state[2][i], w, a2);
    a3 = fmaf(state[3][i], w, a3);
  }
  a0 = siluf(a0); a1 = siluf(a1); a2 = siluf(a2); a3 = siluf(a3);

  // FC2: dot over 128
  const float w2 = W2[j];
  float p0 = a0 * w2, p1 = a1 * w2, p2 = a2 * w2, p3 = a3 * w2;
  for (int mm = 1; mm < 64; mm <<= 1) {
    p0 += __shfl_xor(p0, mm);
    p1 += __shfl_xor(p1, mm);
    p2 += __shfl_xor(p2, mm);
    p3 += __shfl_xor(p3, mm);
  }
  __syncthreads();  // red[] reuse
  if (lane == 0) {
    red[wv * 4 + 0] = p0; red[wv * 4 + 1] = p1;
    red[wv * 4 + 2] = p2; red[wv * 4 + 3] = p3;
  }
  __syncthreads();
  if (j < 4) out[gbase + j] = red[j] + red[4 + j] + b2f[0];
}

extern "C" void kernel_launch(void* const* d_in, const int* in_sizes, int n_in,
                              void* d_out, int out_size, void* d_ws, size_t ws_size,
                              hipStream_t stream) {
  const float* h0  = (const float*)d_in[0];
  const float* h1  = (const float*)d_in[1];
  const float* h2  = (const float*)d_in[2];
  const int*   b0  = (const int*)d_in[3];
  const int*   b1  = (const int*)d_in[4];
  const int*   b2  = (const int*)d_in[5];
  const float* Wg0 = (const float*)d_in[6];
  const float* bg0 = (const float*)d_in[7];
  const float* Wg1 = (const float*)d_in[8];
  const float* bg1 = (const float*)d_in[9];
  const float* Wg2 = (const float*)d_in[10];
  const float* bg2 = (const float*)d_in[11];
  const float* Wp0 = (const float*)d_in[12];
  const float* bp0 = (const float*)d_in[13];
  const float* Wp1 = (const float*)d_in[14];
  const float* bp1 = (const float*)d_in[15];
  const float* Wp2 = (const float*)d_in[16];
  const float* bp2 = (const float*)d_in[17];
  const float* gamma = (const float*)d_in[18];
  const float* beta  = (const float*)d_in[19];
  const float* W1  = (const float*)d_in[20];
  const float* b1f = (const float*)d_in[21];
  const float* W2  = (const float*)d_in[22];
  const float* b2f = (const float*)d_in[23];

  const int N0 = in_sizes[3];
  const int N1 = in_sizes[4];
  const int N2 = in_sizes[5];

  float* ws = (float*)d_ws;

  // init workspace (sums/cnt = 0, max = -inf)
  {
    int blocks = (TOTAL_WS + 255) / 256;
    hipLaunchKernelGGL(init_ws_kernel, dim3(blocks), dim3(256), 0, stream, ws);
  }

  // fused streaming pass over all 3 ranks
  const int nb0 = (N0 + ROWS_PER_BLOCK - 1) / ROWS_PER_BLOCK;
  const int nb1 = (N1 + ROWS_PER_BLOCK - 1) / ROWS_PER_BLOCK;
  const int nb2 = (N2 + ROWS_PER_BLOCK - 1) / ROWS_PER_BLOCK;
  hipLaunchKernelGGL(rank_fused_kernel, dim3(nb0 + nb1 + nb2), dim3(256), 0, stream,
                     h0, b0, Wg0, bg0, N0, nb0,
                     h1, b1, Wg1, bg1, N1, nb1,
                     h2, b2, Wg2, bg2, N2,
                     ws);

  // fused head: agg@Wp -> LN -> SiLU -> FC1 -> SiLU -> FC2
  hipLaunchKernelGGL(finalize_kernel, dim3(B / 4), dim3(128), 0, stream,
                     ws, Wp0, bp0, Wp1, bp1, Wp2, bp2,
                     gamma, beta, W1, b1f, W2, b2f, (float*)d_out);
}